// Round 3
// baseline (50.540 us; speedup 1.0000x reference)
//
#include <hip/hip_runtime.h>

// Problem constants (must match reference)
constexpr int kBImg   = 16384;
constexpr int kG      = 7;
constexpr int kCh     = 30;          // 5*NB + CLS
constexpr int kT      = kBImg * 8;   // 131072 targets
constexpr int kNCells = kBImg * kG * kG;       // 802,816
constexpr int kNFloat = kNCells * kCh;         // 24,084,480 (divisible by 4)
constexpr int kNF4    = kNFloat / 4;           // 6,021,120
constexpr int kBlocks  = 2048;
constexpr int kThreads = 256;

__global__ void loss_init(float* __restrict__ outv) {
    outv[0] = 0.f;
}

__global__ __launch_bounds__(kThreads)
void loss_main(const float* __restrict__ outp,
               const float* __restrict__ tgt,
               float* __restrict__ outv) {
    const int tid    = blockIdx.x * kThreads + threadIdx.x;
    const int stride = kBlocks * kThreads;
    float acc = 0.f;

    // ---- Phase A: lambda_noobj * c^2 over channels 4 and 9 of every cell ----
    // Coalesced float4 scan. Residue r = (4*i) % 30 determines which lane of
    // the float4 (if any) is a confidence:
    //   r==2 -> .z is ch4 ; r==4 -> .x is ch4 ; r==6 -> .w is ch9 ; r==8 -> .y is ch9
    const float4* o4 = reinterpret_cast<const float4*>(outp);
    for (int i = tid; i < kNF4; i += stride) {
        float4 v = o4[i];
        unsigned r = (4u * (unsigned)i) % 30u;
        float c = (r == 2u) ? v.z
                : (r == 4u) ? v.x
                : (r == 6u) ? v.w
                : (r == 8u) ? v.y : 0.f;
        acc += 0.5f * c * c;   // LAMBDA_NOOBJ = 0.5
    }

    // ---- Phase B: per-target terms. Target row = 8 floats:
    //      {x, y, w, h, gx, gy, cls, bid}
    const float4* t4 = reinterpret_cast<const float4*>(tgt);
    for (int t = tid; t < kT; t += stride) {
        float4 ta = t4[2 * t];       // x, y, w, h
        float4 tb = t4[2 * t + 1];   // gx, gy, cls, bid
        float x_t = ta.x, y_t = ta.y, w_t = ta.z, h_t = ta.w;
        int gx    = (int)tb.x;
        int gy    = (int)tb.y;
        int cls_t = (int)tb.z;
        int bid   = (int)tb.w;
        const float* g = outp + ((bid * kG + gx) * kG + gy) * kCh;

        float top_t   = y_t - 3.5f * h_t, bot_t   = y_t + 3.5f * h_t;
        float left_t  = x_t - 3.5f * w_t, right_t = x_t + 3.5f * w_t;
        float area_t  = w_t * h_t * 49.f;

        // box 0
        float x0 = g[0], y0 = g[1], w0 = g[2], h0 = g[3], c0 = g[4];
        float wi0 = fmaxf(fminf(x0 + 3.5f*w0, right_t) - fmaxf(x0 - 3.5f*w0, left_t), 0.f);
        float hi0 = fmaxf(fmaxf(y0 - 3.5f*h0, top_t)   - fminf(y0 + 3.5f*h0, bot_t), 0.f);
        float ai0 = wi0 * hi0;
        float at0 = area_t + w0 * h0 * 49.f - ai0;
        float iou0 = (at0 > 0.f) ? (ai0 / at0) : 0.f;

        // box 1
        float x1 = g[5], y1 = g[6], w1 = g[7], h1 = g[8], c1 = g[9];
        float wi1 = fmaxf(fminf(x1 + 3.5f*w1, right_t) - fmaxf(x1 - 3.5f*w1, left_t), 0.f);
        float hi1 = fmaxf(fmaxf(y1 - 3.5f*h1, top_t)   - fminf(y1 + 3.5f*h1, bot_t), 0.f);
        float ai1 = wi1 * hi1;
        float at1 = area_t + w1 * h1 * 49.f - ai1;
        float iou1 = (at1 > 0.f) ? (ai1 / at1) : 0.f;

        // argmax with first-max-wins tie rule (jnp.argmax)
        bool pick1 = (iou1 > iou0);
        float x_r = pick1 ? x1 : x0;
        float y_r = pick1 ? y1 : y0;
        float w_r = pick1 ? w1 : w0;
        float h_r = pick1 ? h1 : h0;
        float c_r = pick1 ? c1 : c0;

        float dx = x_t - x_r, dy = y_t - y_r;
        float dw = sqrtf(w_t) - sqrtf(w_r);
        float dh = sqrtf(h_t) - sqrtf(h_r);
        acc += 5.f * (dx*dx + dy*dy + dw*dw + dh*dh);      // LAMBDA_COORD
        acc += (c_r - 1.f) * (c_r - 1.f) - 0.5f * c_r * c_r;

        float s = 0.f;
        #pragma unroll
        for (int k = 0; k < 20; ++k) { float cv = g[10 + k]; s += cv * cv; }
        acc += s;
        float clr = g[10 + cls_t];
        acc += (clr - 1.f) * (clr - 1.f) - clr * clr;
    }

    // ---- Deterministic block reduction, then one atomic per block ----
    __shared__ float sm[kThreads];
    sm[threadIdx.x] = acc;
    __syncthreads();
    for (int s = kThreads / 2; s > 0; s >>= 1) {
        if (threadIdx.x < s) sm[threadIdx.x] += sm[threadIdx.x + s];
        __syncthreads();
    }
    if (threadIdx.x == 0) {
        atomicAdd(outv, sm[0] * (1.f / (float)kBImg));
    }
}

extern "C" void kernel_launch(void* const* d_in, const int* in_sizes, int n_in,
                              void* d_out, int out_size, void* d_ws, size_t ws_size,
                              hipStream_t stream) {
    const float* outp = (const float*)d_in[0];   // (16384,7,7,30) f32
    const float* tgt  = (const float*)d_in[1];   // (131072,8) f32
    float* outv       = (float*)d_out;

    loss_init<<<1, 1, 0, stream>>>(outv);
    loss_main<<<kBlocks, kThreads, 0, stream>>>(outp, tgt, outv);
}